// Round 1
// baseline (589.030 us; speedup 1.0000x reference)
//
#include <hip/hip_runtime.h>
#include <math.h>

#define B_   4
#define N_   512
#define T_   128
#define F_   64
#define GSZ  (B_ * T_)   // 512 groups (b*T + t)
#define QT   64
#define KT   64
#define LD   68          // LDS row stride in floats; 68*4=272B = 17*16B -> float4-aligned rows

__global__ __launch_bounds__(256, 2)
void sgcn_attn_kernel(const float* __restrict__ x,
                      const float* __restrict__ adj,
                      const float* __restrict__ theta,
                      float* __restrict__ out)
{
    __shared__ float lds[3 * QT * LD];
    float (*Qs)[LD] = (float (*)[LD])lds;                 // Q tile; reused for Theta^T in epilogue
    float (*Ks)[LD] = (float (*)[LD])(lds + QT * LD);     // K tile
    float (*Ps)[LD] = (float (*)[LD])(lds + 2 * QT * LD); // P tile; reused for Agg in epilogue

    const int tid = threadIdx.x;
    const int g   = blockIdx.y;        // group = b*T + t
    const int b   = g / T_;
    const int t   = g - b * T_;
    const int q0  = blockIdx.x * QT;

    const int rg  = tid >> 4;          // 0..15 : row-quad id
    const int j16 = tid & 15;          // 0..15 : lane within row group
    const int r0  = rg * 4;            // this thread's 4 rows
    const int f0  = j16 * 4;           // this thread's 4 feature cols (PV/epilogue)

    const int nstride = T_ * F_;       // 8192 floats between consecutive n
    const float* xg = x + ((b * N_) * T_ + t) * F_;   // + n*nstride + f

    // ---- load Q tile (64 rows x 64 f) ----
    #pragma unroll
    for (int k = 0; k < 4; ++k) {
        int lin = tid + k * 256;       // 0..1023 float4 slots
        int row = lin >> 4;
        int c   = (lin & 15) * 4;
        float4 v = *(const float4*)(xg + (q0 + row) * nstride + c);
        *(float4*)&Qs[row][c] = v;
    }

    float4 acc[4];
    float  m_run[4], l_run[4];
    #pragma unroll
    for (int i = 0; i < 4; ++i) {
        acc[i] = make_float4(0.f, 0.f, 0.f, 0.f);
        m_run[i] = -INFINITY;
        l_run[i] = 0.f;
    }

    for (int k0 = 0; k0 < N_; k0 += KT) {
        __syncthreads();               // prev iter done reading Ks/Ps

        // ---- load K tile ----
        #pragma unroll
        for (int k = 0; k < 4; ++k) {
            int lin = tid + k * 256;
            int row = lin >> 4;
            int c   = (lin & 15) * 4;
            float4 v = *(const float4*)(xg + (k0 + row) * nstride + c);
            *(float4*)&Ks[row][c] = v;
        }

        // adj values for this (qtile, ktile): adj[q0+r][k0+m], m = j16 + jj*16
        float a_r[4][4];
        #pragma unroll
        for (int i = 0; i < 4; ++i)
            #pragma unroll
            for (int jj = 0; jj < 4; ++jj)
                a_r[i][jj] = adj[(q0 + r0 + i) * N_ + k0 + j16 + jj * 16];

        __syncthreads();               // K tile ready

        // ---- QK^T : s[i][jj] = dot(Q[r0+i], K[j16+jj*16]) ----
        float s[4][4];
        #pragma unroll
        for (int i = 0; i < 4; ++i)
            #pragma unroll
            for (int jj = 0; jj < 4; ++jj)
                s[i][jj] = 0.f;

        #pragma unroll
        for (int f = 0; f < F_; f += 4) {
            float4 qv[4], kv[4];
            #pragma unroll
            for (int i = 0; i < 4; ++i)  qv[i]  = *(const float4*)&Qs[r0 + i][f];
            #pragma unroll
            for (int jj = 0; jj < 4; ++jj) kv[jj] = *(const float4*)&Ks[j16 + jj * 16][f];
            #pragma unroll
            for (int i = 0; i < 4; ++i)
                #pragma unroll
                for (int jj = 0; jj < 4; ++jj)
                    s[i][jj] = fmaf(qv[i].x, kv[jj].x,
                               fmaf(qv[i].y, kv[jj].y,
                               fmaf(qv[i].z, kv[jj].z,
                               fmaf(qv[i].w, kv[jj].w, s[i][jj]))));
        }

        // ---- online softmax (per row, across 16 lanes) ----
        float p[4][4];
        #pragma unroll
        for (int i = 0; i < 4; ++i) {
            #pragma unroll
            for (int jj = 0; jj < 4; ++jj)
                s[i][jj] *= 0.125f;    // 1/sqrt(F_in)

            float tmax = fmaxf(fmaxf(s[i][0], s[i][1]), fmaxf(s[i][2], s[i][3]));
            #pragma unroll
            for (int off = 1; off < 16; off <<= 1)
                tmax = fmaxf(tmax, __shfl_xor(tmax, off));

            float m_new = fmaxf(m_run[i], tmax);
            float scale = __expf(m_run[i] - m_new);

            float rsum = 0.f;
            #pragma unroll
            for (int jj = 0; jj < 4; ++jj) {
                float e = __expf(s[i][jj] - m_new);
                rsum += e;
                p[i][jj] = e * a_r[i][jj];   // adj masks numerator only
            }
            #pragma unroll
            for (int off = 1; off < 16; off <<= 1)
                rsum += __shfl_xor(rsum, off);

            l_run[i] = l_run[i] * scale + rsum;
            m_run[i] = m_new;

            acc[i].x *= scale; acc[i].y *= scale; acc[i].z *= scale; acc[i].w *= scale;
        }

        // ---- write P tile ----
        #pragma unroll
        for (int i = 0; i < 4; ++i)
            #pragma unroll
            for (int jj = 0; jj < 4; ++jj)
                Ps[r0 + i][j16 + jj * 16] = p[i][jj];

        __syncthreads();               // P ready

        // ---- PV : acc[i][0..3] += sum_m P[r0+i][m] * K[m][f0..f0+3] ----
        #pragma unroll
        for (int m = 0; m < KT; m += 4) {
            float4 pr[4], kv[4];
            #pragma unroll
            for (int i = 0; i < 4; ++i)   pr[i]  = *(const float4*)&Ps[r0 + i][m];
            #pragma unroll
            for (int mm = 0; mm < 4; ++mm) kv[mm] = *(const float4*)&Ks[m + mm][f0];
            #pragma unroll
            for (int i = 0; i < 4; ++i) {
                acc[i].x = fmaf(pr[i].x, kv[0].x, fmaf(pr[i].y, kv[1].x, fmaf(pr[i].z, kv[2].x, fmaf(pr[i].w, kv[3].x, acc[i].x))));
                acc[i].y = fmaf(pr[i].x, kv[0].y, fmaf(pr[i].y, kv[1].y, fmaf(pr[i].z, kv[2].y, fmaf(pr[i].w, kv[3].y, acc[i].y))));
                acc[i].z = fmaf(pr[i].x, kv[0].z, fmaf(pr[i].y, kv[1].z, fmaf(pr[i].z, kv[2].z, fmaf(pr[i].w, kv[3].z, acc[i].z))));
                acc[i].w = fmaf(pr[i].x, kv[0].w, fmaf(pr[i].y, kv[1].w, fmaf(pr[i].z, kv[2].w, fmaf(pr[i].w, kv[3].w, acc[i].w))));
            }
        }
    }

    __syncthreads();                   // all PV done; Qs/Ps reusable

    // ---- normalized agg -> Ps ; Theta^T -> Qs ----
    #pragma unroll
    for (int i = 0; i < 4; ++i) {
        float inv = 0.125f / l_run[i]; // softmax denom + second 1/sqrt(F_in)
        float4 a = make_float4(acc[i].x * inv, acc[i].y * inv, acc[i].z * inv, acc[i].w * inv);
        *(float4*)&Ps[r0 + i][f0] = a;
    }
    #pragma unroll
    for (int k = 0; k < 4; ++k) {
        int lin = tid + k * 256;       // 1024 float4 slots = 4096 floats
        int fo  = lin >> 4;
        int fi  = (lin & 15) * 4;
        float4 v = *(const float4*)(theta + fo * F_ + fi);
        Qs[fi + 0][fo] = v.x;          // Qs[fi][fo] = Theta[fo][fi]
        Qs[fi + 1][fo] = v.y;
        Qs[fi + 2][fo] = v.z;
        Qs[fi + 3][fo] = v.w;
    }
    __syncthreads();

    // ---- out[r][fo] = relu( sum_fi Agg[r][fi] * Theta[fo][fi] ) ----
    float4 o[4];
    #pragma unroll
    for (int i = 0; i < 4; ++i) o[i] = make_float4(0.f, 0.f, 0.f, 0.f);

    #pragma unroll
    for (int fi = 0; fi < F_; fi += 4) {
        float4 ag[4], tv[4];
        #pragma unroll
        for (int i = 0; i < 4; ++i)   ag[i]  = *(const float4*)&Ps[r0 + i][fi];
        #pragma unroll
        for (int ff = 0; ff < 4; ++ff) tv[ff] = *(const float4*)&Qs[fi + ff][f0];
        #pragma unroll
        for (int i = 0; i < 4; ++i) {
            o[i].x = fmaf(ag[i].x, tv[0].x, fmaf(ag[i].y, tv[1].x, fmaf(ag[i].z, tv[2].x, fmaf(ag[i].w, tv[3].x, o[i].x))));
            o[i].y = fmaf(ag[i].x, tv[0].y, fmaf(ag[i].y, tv[1].y, fmaf(ag[i].z, tv[2].y, fmaf(ag[i].w, tv[3].y, o[i].y))));
            o[i].z = fmaf(ag[i].x, tv[0].z, fmaf(ag[i].y, tv[1].z, fmaf(ag[i].z, tv[2].z, fmaf(ag[i].w, tv[3].z, o[i].z))));
            o[i].w = fmaf(ag[i].x, tv[0].w, fmaf(ag[i].y, tv[1].w, fmaf(ag[i].z, tv[2].w, fmaf(ag[i].w, tv[3].w, o[i].w))));
        }
    }

    #pragma unroll
    for (int i = 0; i < 4; ++i) {
        float4 v = o[i];
        v.x = fmaxf(v.x, 0.f); v.y = fmaxf(v.y, 0.f);
        v.z = fmaxf(v.z, 0.f); v.w = fmaxf(v.w, 0.f);
        // out[b][n][t][fo], n = q0+r0+i
        *(float4*)(out + ((b * N_ + q0 + r0 + i) * T_ + t) * F_ + f0) = v;
    }
}

extern "C" void kernel_launch(void* const* d_in, const int* in_sizes, int n_in,
                              void* d_out, int out_size, void* d_ws, size_t ws_size,
                              hipStream_t stream) {
    const float* x     = (const float*)d_in[0];
    const float* adj   = (const float*)d_in[1];
    const float* theta = (const float*)d_in[2];
    float* out = (float*)d_out;

    dim3 grid(N_ / QT, GSZ);   // (8, 512) = 4096 blocks
    sgcn_attn_kernel<<<grid, 256, 0, stream>>>(x, adj, theta, out);
}

// Round 2
// 148.494 us; speedup vs baseline: 3.9667x; 3.9667x over previous
//
#include <hip/hip_runtime.h>
#include <math.h>

#define B_   4
#define N_   512
#define T_   128
#define F_   64
#define QT   128
#define KT   64
#define NSTR (T_*F_)   // 8192 floats between consecutive n
#define RS   144       // LDS row stride in bytes (72 bf16), multiple of 16

typedef __attribute__((ext_vector_type(8))) short  s8v;   // 8 x bf16 payload
typedef __attribute__((ext_vector_type(4))) float  f4v;

union F8 { s8v v; unsigned u[4]; };

// byte offset into an LDS tile: row stride RS, 16B-chunk XOR swizzle
__device__ __forceinline__ int swz(int row, int col /*bf16 units*/) {
    return row*RS + ((((col>>3) ^ (row>>3)) & 7) << 4) + ((col & 7) << 1);
}

__device__ __forceinline__ unsigned cvt_pk(float lo, float hi) {
    unsigned r;
    asm("v_cvt_pk_bf16_f32 %0, %1, %2" : "=v"(r) : "v"(lo), "v"(hi));
    return r;
}

__global__ __launch_bounds__(256, 2)
void sgcn_mfma_kernel(const float* __restrict__ x,
                      const float* __restrict__ adj,
                      const float* __restrict__ theta,
                      float* __restrict__ out)
{
    __shared__ char lds[(2*64 + 128) * RS];   // 36864 B
    char* Xrow = lds;              // [64 n][64 f] bf16, feat-contiguous  (QK B-frags)
    char* Xcol = lds + 64*RS;      // [64 f][64 n] bf16, n-contiguous     (PV B-frags)
    char* Pb   = lds + 128*RS;     // [128 q][64 m] bf16, P tile; reused for O

    const int tid  = threadIdx.x;
    const int lane = tid & 63;
    const int w    = tid >> 6;     // wave 0..3, owns Q rows 32w..32w+31
    const int c15  = lane & 15;
    const int g4   = lane >> 4;    // 0..3

    const int g  = blockIdx.y;     // group = b*T + t
    const int b  = g / T_;
    const int t  = g - b*T_;
    const int q0 = blockIdx.x * QT;

    const float* xg = x + (size_t)b*N_*T_*F_ + (size_t)t*F_;   // + n*NSTR + f

    // ---- Q A-fragments (held in registers for the whole kernel) ----
    // A layout (16x16x32): row = lane&15, k = (lane>>4)*8 + j
    F8 qf[2][2];
    #pragma unroll
    for (int rt = 0; rt < 2; ++rt)
      #pragma unroll
      for (int kk = 0; kk < 2; ++kk) {
        const float* qp = xg + (q0 + 32*w + 16*rt + c15)*NSTR + 32*kk + 8*g4;
        float4 a = *(const float4*)qp;
        float4 c = *(const float4*)(qp + 4);
        qf[rt][kk].u[0] = cvt_pk(a.x, a.y);
        qf[rt][kk].u[1] = cvt_pk(a.z, a.w);
        qf[rt][kk].u[2] = cvt_pk(c.x, c.y);
        qf[rt][kk].u[3] = cvt_pk(c.z, c.w);
      }

    f4v  O[2][4];
    float l_acc[2][4];
    #pragma unroll
    for (int rt = 0; rt < 2; ++rt)
      #pragma unroll
      for (int cc = 0; cc < 4; ++cc) O[rt][cc] = (f4v)0.f;
    #pragma unroll
    for (int rt = 0; rt < 2; ++rt)
      #pragma unroll
      for (int r = 0; r < 4; ++r) l_acc[rt][r] = 0.f;

    for (int kt = 0; kt < N_/KT; ++kt) {
        const int k0 = kt * KT;

        // ---- issue global loads for the X k-tile (before the barrier) ----
        float4 xv[4];
        #pragma unroll
        for (int it = 0; it < 4; ++it) {
            int idx  = tid + it*256;          // 0..1023 float4 slots
            int row  = idx >> 4;              // 0..63
            int col4 = (idx & 15) * 4;        // 0..60
            xv[it] = *(const float4*)(xg + (k0 + row)*NSTR + col4);
        }

        __syncthreads();   // previous iteration done reading Xrow/Xcol

        // ---- stage as bf16 into Xrow (row-major) and Xcol (transposed) ----
        #pragma unroll
        for (int it = 0; it < 4; ++it) {
            int idx  = tid + it*256;
            int row  = idx >> 4;
            int col4 = (idx & 15) * 4;
            unsigned p0 = cvt_pk(xv[it].x, xv[it].y);
            unsigned p1 = cvt_pk(xv[it].z, xv[it].w);
            *(uint2*)(Xrow + swz(row, col4)) = make_uint2(p0, p1);
            *(unsigned short*)(Xcol + swz(col4 + 0, row)) = (unsigned short)(p0);
            *(unsigned short*)(Xcol + swz(col4 + 1, row)) = (unsigned short)(p0 >> 16);
            *(unsigned short*)(Xcol + swz(col4 + 2, row)) = (unsigned short)(p1);
            *(unsigned short*)(Xcol + swz(col4 + 3, row)) = (unsigned short)(p1 >> 16);
        }

        __syncthreads();   // X tile ready

        // ---- adj values for this (q-rows, k-tile) ----
        float adjv[2][4][4];
        #pragma unroll
        for (int rt = 0; rt < 2; ++rt)
          #pragma unroll
          for (int r = 0; r < 4; ++r) {
            const float* ap = adj + (q0 + 32*w + 16*rt + 4*g4 + r)*N_ + k0 + c15;
            #pragma unroll
            for (int cc = 0; cc < 4; ++cc) adjv[rt][r][cc] = ap[16*cc];
          }

        // ---- QK^T: S[rt][cc] (C layout: row = 16rt+4*g4+reg, col = 16cc+c15) ----
        f4v S[2][4];
        #pragma unroll
        for (int rt = 0; rt < 2; ++rt)
          #pragma unroll
          for (int cc = 0; cc < 4; ++cc) S[rt][cc] = (f4v)0.f;

        #pragma unroll
        for (int kk = 0; kk < 2; ++kk)
          #pragma unroll
          for (int cc = 0; cc < 4; ++cc) {
            F8 bf;
            bf.v = *(const s8v*)(Xrow + swz(16*cc + c15, 32*kk + 8*g4));
            #pragma unroll
            for (int rt = 0; rt < 2; ++rt)
              S[rt][cc] = __builtin_amdgcn_mfma_f32_16x16x32_bf16(qf[rt][kk].v, bf.v, S[rt][cc], 0, 0, 0);
          }

        // ---- softmax numerators (no max-subtraction: logits bounded) + P->LDS ----
        #pragma unroll
        for (int rt = 0; rt < 2; ++rt)
          #pragma unroll
          for (int cc = 0; cc < 4; ++cc) {
            #pragma unroll
            for (int r = 0; r < 4; ++r) {
                float e = __expf(S[rt][cc][r] * 0.125f);
                l_acc[rt][r] += e;                       // unmasked row sum
                float pm = e * adjv[rt][r][cc];          // adj masks numerator only
                float nb = __shfl_xor(pm, 1);            // partner holds m^1
                if ((lane & 1) == 0) {
                    unsigned pk = cvt_pk(pm, nb);
                    *(unsigned*)(Pb + swz(32*w + 16*rt + 4*g4 + r, 16*cc + c15)) = pk;
                }
            }
          }

        // ---- PV: O += P * V  (P rows are wave-private; waitcnt orders RAW) ----
        #pragma unroll
        for (int kk = 0; kk < 2; ++kk) {
            F8 pa[2];
            #pragma unroll
            for (int rt = 0; rt < 2; ++rt)
                pa[rt].v = *(const s8v*)(Pb + swz(32*w + 16*rt + c15, 32*kk + 8*g4));
            #pragma unroll
            for (int cc = 0; cc < 4; ++cc) {
                F8 vb;
                vb.v = *(const s8v*)(Xcol + swz(16*cc + c15, 32*kk + 8*g4));
                #pragma unroll
                for (int rt = 0; rt < 2; ++rt)
                    O[rt][cc] = __builtin_amdgcn_mfma_f32_16x16x32_bf16(pa[rt].v, vb.v, O[rt][cc], 0, 0, 0);
            }
        }
    }

    // ---- finalize softmax denominators ----
    float inv[2][4];
    #pragma unroll
    for (int rt = 0; rt < 2; ++rt)
      #pragma unroll
      for (int r = 0; r < 4; ++r) {
        float lv = l_acc[rt][r];
        #pragma unroll
        for (int off = 1; off < 16; off <<= 1) lv += __shfl_xor(lv, off);
        inv[rt][r] = 0.125f / lv;    // softmax denom + second 1/sqrt(F_in)
      }

    __syncthreads();   // done with Xrow/Xcol/P from main loop

    // ---- write normalized agg (bf16) into Pb, reused as O-tile ----
    #pragma unroll
    for (int rt = 0; rt < 2; ++rt)
      #pragma unroll
      for (int cc = 0; cc < 4; ++cc)
        #pragma unroll
        for (int r = 0; r < 4; ++r) {
            float ov = O[rt][cc][r] * inv[rt][r];
            float nb = __shfl_xor(ov, 1);
            if ((lane & 1) == 0) {
                unsigned pk = cvt_pk(ov, nb);
                *(unsigned*)(Pb + swz(32*w + 16*rt + 4*g4 + r, 16*cc + c15)) = pk;
            }
        }

    // ---- Theta^T B-frags from global (L1/L2-hot) ----
    F8 tb[2][4];   // [kk][cc]
    #pragma unroll
    for (int kk = 0; kk < 2; ++kk)
      #pragma unroll
      for (int cc = 0; cc < 4; ++cc) {
        const float* tp = theta + (16*cc + c15)*F_ + 32*kk + 8*g4;
        float4 a = *(const float4*)tp;
        float4 c = *(const float4*)(tp + 4);
        tb[kk][cc].u[0] = cvt_pk(a.x, a.y);
        tb[kk][cc].u[1] = cvt_pk(a.z, a.w);
        tb[kk][cc].u[2] = cvt_pk(c.x, c.y);
        tb[kk][cc].u[3] = cvt_pk(c.z, c.w);
      }

    // ---- out = relu(agg @ Theta^T) ----
    f4v R[2][4];
    #pragma unroll
    for (int rt = 0; rt < 2; ++rt)
      #pragma unroll
      for (int cc = 0; cc < 4; ++cc) R[rt][cc] = (f4v)0.f;

    #pragma unroll
    for (int kk = 0; kk < 2; ++kk) {
        F8 oa[2];
        #pragma unroll
        for (int rt = 0; rt < 2; ++rt)
            oa[rt].v = *(const s8v*)(Pb + swz(32*w + 16*rt + c15, 32*kk + 8*g4));
        #pragma unroll
        for (int cc = 0; cc < 4; ++cc)
            #pragma unroll
            for (int rt = 0; rt < 2; ++rt)
                R[rt][cc] = __builtin_amdgcn_mfma_f32_16x16x32_bf16(oa[rt].v, tb[kk][cc].v, R[rt][cc], 0, 0, 0);
    }

    #pragma unroll
    for (int rt = 0; rt < 2; ++rt)
      #pragma unroll
      for (int cc = 0; cc < 4; ++cc)
        #pragma unroll
        for (int r = 0; r < 4; ++r) {
            float v = fmaxf(R[rt][cc][r], 0.f);
            int q  = q0 + 32*w + 16*rt + 4*g4 + r;
            int fo = 16*cc + c15;
            out[((b*N_ + q)*T_ + t)*F_ + fo] = v;
        }
}

extern "C" void kernel_launch(void* const* d_in, const int* in_sizes, int n_in,
                              void* d_out, int out_size, void* d_ws, size_t ws_size,
                              hipStream_t stream) {
    const float* x     = (const float*)d_in[0];
    const float* adj   = (const float*)d_in[1];
    const float* theta = (const float*)d_in[2];
    float* out = (float*)d_out;

    dim3 grid(N_ / QT, B_ * T_);   // (4, 512) = 2048 blocks
    sgcn_mfma_kernel<<<grid, 256, 0, stream>>>(x, adj, theta, out);
}

// Round 3
// 106.578 us; speedup vs baseline: 5.5267x; 1.3933x over previous
//
#include <hip/hip_runtime.h>
#include <math.h>

#define B_   4
#define N_   512
#define T_   128
#define F_   64
#define QT   128
#define NSTR (T_*F_)   // 8192 floats between consecutive n
#define RSR  144       // Xrow row stride (bytes)
#define RSC  136       // Xcol row stride (bytes), 8B-aligned rows for b64

typedef __attribute__((ext_vector_type(8))) short  s8v;
typedef __attribute__((ext_vector_type(4))) float  f4v;

union F8 { s8v v; unsigned u[4]; uint2 u2[2]; };

// Xrow: row-major [n][f] bf16, 16B-chunk XOR swizzle (validated in round 2)
__device__ __forceinline__ int swzR(int row, int col /*bf16 units*/) {
    return row*RSR + ((((col>>3) ^ (row>>3)) & 7) << 4) + ((col & 7) << 1);
}

__device__ __forceinline__ unsigned cvt_pk(float lo, float hi) {
    unsigned r;
    asm("v_cvt_pk_bf16_f32 %0, %1, %2" : "=v"(r) : "v"(lo), "v"(hi));
    return r;
}

__global__ __launch_bounds__(256, 2)
void sgcn_mfma2_kernel(const float* __restrict__ x,
                       const float* __restrict__ adj,
                       const float* __restrict__ theta,
                       float* __restrict__ out)
{
    __shared__ char ldsbuf[64*RSR + 64*RSC];   // 17920 B
    char* Xrow = ldsbuf;             // [64 n][64 f] bf16 (QK A-frags, f-contiguous)
    char* Xcol = ldsbuf + 64*RSR;    // [64 f][64 n] bf16 (PV A-frags, n-contiguous)

    const int tid  = threadIdx.x;
    const int lane = tid & 63;
    const int w    = tid >> 6;       // wave 0..3
    const int c15  = lane & 15;
    const int g4   = lane >> 4;      // 0..3

    const int g  = blockIdx.y;       // group = b*T + t
    const int b  = g >> 7;
    const int t  = g & 127;
    const int q0 = blockIdx.x*QT + 32*w;   // this wave's q-base (32 rows)

    const float* xg = x + (size_t)b*N_*NSTR + (size_t)t*F_;   // + n*NSTR + f

    // ---- Q as B-fragments (swapped QK: S^T = K * Q^T), held all kernel ----
    // B layout: col = lane&15 (q), k = (lane>>4)*8 + j (f)
    F8 qf[2][2];   // [qt][kk]
    #pragma unroll
    for (int qt = 0; qt < 2; ++qt)
      #pragma unroll
      for (int kk = 0; kk < 2; ++kk) {
        const float* qp = xg + (size_t)(q0 + 16*qt + c15)*NSTR + 32*kk + 8*g4;
        float4 a = *(const float4*)qp;
        float4 c = *(const float4*)(qp + 4);
        qf[qt][kk].u[0] = cvt_pk(a.x, a.y);
        qf[qt][kk].u[1] = cvt_pk(a.z, a.w);
        qf[qt][kk].u[2] = cvt_pk(c.x, c.y);
        qf[qt][kk].u[3] = cvt_pk(c.z, c.w);
      }

    f4v  Oacc[4][2];   // O^T accumulators [ft][qt]
    float l_acc[2] = {0.f, 0.f};
    #pragma unroll
    for (int ft = 0; ft < 4; ++ft)
      #pragma unroll
      for (int qt = 0; qt < 2; ++qt) Oacc[ft][qt] = (f4v)0.f;

    const int nrow = tid >> 4;       // 0..15 : my staging row (per it: +16*it)
    const int nb   = 4*w;            // my quad's n-base within a 16-row slab

    // prologue: load k-tile 0
    float4 xv[4];
    #pragma unroll
    for (int it = 0; it < 4; ++it)
        xv[it] = *(const float4*)(xg + (size_t)(nrow + 16*it)*NSTR + 4*c15);

    for (int kt = 0; kt < 8; ++kt) {
        __syncthreads();   // all waves done reading LDS of previous tile

        // ---- stage X k-tile: Xrow (direct) + Xcol (register 4x4 transpose) ----
        #pragma unroll
        for (int it = 0; it < 4; ++it) {
            int n = nrow + 16*it;
            unsigned p0 = cvt_pk(xv[it].x, xv[it].y);   // f = 4c15+0,1 @ my n
            unsigned p1 = cvt_pk(xv[it].z, xv[it].w);   // f = 4c15+2,3
            *(uint2*)(Xrow + swzR(n, 4*c15)) = make_uint2(p0, p1);

            // quad {lane, lane^16, lane^32, lane^48} holds n = 4w+16it+{0..3},
            // same f-range 4c15..4c15+3. Lane ends with f = 4c15+g4, all 4 n.
            unsigned t0 = (unsigned)__shfl_xor((int)p0, 16);
            unsigned t1 = (unsigned)__shfl_xor((int)p1, 16);
            unsigned a  = (g4 & 2) ? p1 : p0;   // pair containing my f
            unsigned ta = (g4 & 2) ? t1 : t0;
            unsigned bq = (g4 & 2) ? p0 : p1;   // pair for xor-32 partner's f
            unsigned tb = (g4 & 2) ? t0 : t1;
            unsigned u_mine = (g4 & 1) ? ((ta >> 16) | (a  & 0xffff0000u))
                                       : ((a  & 0xffffu) | (ta << 16));
            unsigned u_oth  = (g4 & 1) ? ((tb >> 16) | (bq & 0xffff0000u))
                                       : ((bq & 0xffffu) | (tb << 16));
            unsigned v2 = (unsigned)__shfl_xor((int)u_oth, 32);
            uint2 wv = (g4 & 2) ? make_uint2(v2, u_mine) : make_uint2(u_mine, v2);
            *(uint2*)(Xcol + (4*c15 + g4)*RSC + (nb + 16*it)*2) = wv;
        }

        __syncthreads();   // X tile ready

        // ---- prefetch next k-tile (in flight across compute phase) ----
        if (kt < 7) {
            #pragma unroll
            for (int it = 0; it < 4; ++it)
                xv[it] = *(const float4*)(xg + (size_t)((kt+1)*64 + nrow + 16*it)*NSTR + 4*c15);
        }

        // ---- adj tile, vectorized: adj[q][k0 + 16mt + 4g4 .. +3] ----
        float4 adjv[2][4];
        #pragma unroll
        for (int qt = 0; qt < 2; ++qt)
          #pragma unroll
          for (int mt = 0; mt < 4; ++mt)
            adjv[qt][mt] = *(const float4*)(adj + (size_t)(q0 + 16*qt + c15)*N_ + kt*64 + 16*mt + 4*g4);

        // ---- QK^T swapped: S^T[m][q] = sum_f K[m][f] Q^T[f][q] ----
        f4v S[4][2];
        #pragma unroll
        for (int mt = 0; mt < 4; ++mt)
          #pragma unroll
          for (int qt = 0; qt < 2; ++qt) S[mt][qt] = (f4v)0.f;

        #pragma unroll
        for (int kk = 0; kk < 2; ++kk)
          #pragma unroll
          for (int mt = 0; mt < 4; ++mt) {
            F8 af;   // A: row = c15 (m), k = 8g4+j (f)
            af.v = *(const s8v*)(Xrow + swzR(16*mt + c15, 32*kk + 8*g4));
            #pragma unroll
            for (int qt = 0; qt < 2; ++qt)
              S[mt][qt] = __builtin_amdgcn_mfma_f32_16x16x32_bf16(af.v, qf[qt][kk].v, S[mt][qt], 0, 0, 0);
          }

        // ---- softmax numerators (logits bounded; no max-subtraction) ----
        // P^T is lane-local: pack straight into PV B-frags. k-slot map (both
        // operands): j=0..3 -> m = 16*(2kk)+4g4+j ; j=4..7 -> m = 16*(2kk+1)+4g4+j-4
        F8 pb[2][2];   // [qt][kk]
        #pragma unroll
        for (int qt = 0; qt < 2; ++qt)
          #pragma unroll
          for (int mt = 0; mt < 4; ++mt) {
            float e0 = __expf(S[mt][qt][0] * 0.125f);
            float e1 = __expf(S[mt][qt][1] * 0.125f);
            float e2 = __expf(S[mt][qt][2] * 0.125f);
            float e3 = __expf(S[mt][qt][3] * 0.125f);
            l_acc[qt] += (e0 + e1) + (e2 + e3);          // unmasked row sum
            float4 av = adjv[qt][mt];
            pb[qt][mt>>1].u[2*(mt&1)  ] = cvt_pk(e0*av.x, e1*av.y);
            pb[qt][mt>>1].u[2*(mt&1)+1] = cvt_pk(e2*av.z, e3*av.w);
          }

        // ---- PV swapped: O^T[f][q] += sum_m V^T[f][m] P^T[m][q] ----
        #pragma unroll
        for (int kk = 0; kk < 2; ++kk)
          #pragma unroll
          for (int ft = 0; ft < 4; ++ft) {
            F8 vf;   // A: row = c15 (f), k-slots j0..3: m=32kk+4g4+j ; j4..7: m=32kk+16+4g4+j
            vf.u2[0] = *(const uint2*)(Xcol + (16*ft + c15)*RSC + 64*kk + 8*g4);
            vf.u2[1] = *(const uint2*)(Xcol + (16*ft + c15)*RSC + 64*kk + 32 + 8*g4);
            #pragma unroll
            for (int qt = 0; qt < 2; ++qt)
              Oacc[ft][qt] = __builtin_amdgcn_mfma_f32_16x16x32_bf16(vf.v, pb[qt][kk].v, Oacc[ft][qt], 0, 0, 0);
          }
    }

    // ---- softmax denominators: reduce over g4 groups ----
    float inv[2];
    #pragma unroll
    for (int qt = 0; qt < 2; ++qt) {
        float lv = l_acc[qt];
        lv += __shfl_xor(lv, 16);
        lv += __shfl_xor(lv, 32);
        inv[qt] = 0.125f / lv;     // softmax denom + second 1/sqrt(F_in)
    }

    // ---- B-frags from O^T (lane-local), scaled by inv ----
    F8 ob[2][2];   // [qt][kk]
    #pragma unroll
    for (int qt = 0; qt < 2; ++qt)
      #pragma unroll
      for (int kk = 0; kk < 2; ++kk) {
        f4v o0 = Oacc[2*kk][qt], o1 = Oacc[2*kk+1][qt];
        ob[qt][kk].u[0] = cvt_pk(o0[0]*inv[qt], o0[1]*inv[qt]);
        ob[qt][kk].u[1] = cvt_pk(o0[2]*inv[qt], o0[3]*inv[qt]);
        ob[qt][kk].u[2] = cvt_pk(o1[0]*inv[qt], o1[1]*inv[qt]);
        ob[qt][kk].u[3] = cvt_pk(o1[2]*inv[qt], o1[3]*inv[qt]);
      }

    // ---- Theta A-frags (same k-permutation as ob) ----
    F8 tf[4][2];   // [ot][kk]
    #pragma unroll
    for (int ot = 0; ot < 4; ++ot)
      #pragma unroll
      for (int kk = 0; kk < 2; ++kk) {
        const float* tp = theta + (size_t)(16*ot + c15)*F_ + 32*kk + 4*g4;
        float4 a = *(const float4*)tp;          // fi = 32kk+4g4 + 0..3
        float4 c = *(const float4*)(tp + 16);   // fi = 32kk+16+4g4 + 0..3
        tf[ot][kk].u[0] = cvt_pk(a.x, a.y);
        tf[ot][kk].u[1] = cvt_pk(a.z, a.w);
        tf[ot][kk].u[2] = cvt_pk(c.x, c.y);
        tf[ot][kk].u[3] = cvt_pk(c.z, c.w);
      }

    // ---- R^T = Theta * (O^T * inv) ----
    f4v R[4][2];
    #pragma unroll
    for (int ot = 0; ot < 4; ++ot)
      #pragma unroll
      for (int qt = 0; qt < 2; ++qt) R[ot][qt] = (f4v)0.f;

    #pragma unroll
    for (int kk = 0; kk < 2; ++kk)
      #pragma unroll
      for (int ot = 0; ot < 4; ++ot)
        #pragma unroll
        for (int qt = 0; qt < 2; ++qt)
          R[ot][qt] = __builtin_amdgcn_mfma_f32_16x16x32_bf16(tf[ot][kk].v, ob[qt][kk].v, R[ot][qt], 0, 0, 0);

    // ---- relu + store: lane holds R^T[fo=16ot+4g4+r][q=16qt+c15] -> float4 over r ----
    #pragma unroll
    for (int ot = 0; ot < 4; ++ot)
      #pragma unroll
      for (int qt = 0; qt < 2; ++qt) {
        float4 v;
        v.x = fmaxf(R[ot][qt][0], 0.f);
        v.y = fmaxf(R[ot][qt][1], 0.f);
        v.z = fmaxf(R[ot][qt][2], 0.f);
        v.w = fmaxf(R[ot][qt][3], 0.f);
        int q  = q0 + 16*qt + c15;
        int fo = 16*ot + 4*g4;
        *(float4*)(out + ((size_t)(b*N_ + q)*T_ + t)*F_ + fo) = v;
      }
}

extern "C" void kernel_launch(void* const* d_in, const int* in_sizes, int n_in,
                              void* d_out, int out_size, void* d_ws, size_t ws_size,
                              hipStream_t stream) {
    const float* x     = (const float*)d_in[0];
    const float* adj   = (const float*)d_in[1];
    const float* theta = (const float*)d_in[2];
    float* out = (float*)d_out;

    dim3 grid(N_ / QT, B_ * T_);   // (4, 512) = 2048 blocks
    sgcn_mfma2_kernel<<<grid, 256, 0, stream>>>(x, adj, theta, out);
}